// Round 6
// baseline (773.189 us; speedup 1.0000x reference)
//
#include <hip/hip_runtime.h>

// ---------- types / helpers ----------
typedef __bf16 bf16x8 __attribute__((ext_vector_type(8)));
typedef unsigned short u16x8 __attribute__((ext_vector_type(8)));
typedef float f32x4 __attribute__((ext_vector_type(4)));

union BU {
    u16x8 u;
    bf16x8 b;
};

static __device__ __forceinline__ float b2f(unsigned short u) {
    return __uint_as_float(((unsigned)u) << 16);
}
static __device__ __forceinline__ unsigned short f2b(float f) {
    unsigned u = __float_as_uint(f);
    unsigned r = (u + 0x7FFF + ((u >> 16) & 1)) >> 16;  // RNE
    return (unsigned short)r;
}

// Sliced activation layout: elem(node, f) at buf[((f>>4)*Nn + node)*16 + (f&15)].
// Each 16-feature slice is Nn*32 bytes (3.2 MB @ N=100k) -> fits one XCD L2.

// ---------- fused prep: round(x->xb sliced) || deg atomics, then wsplit + bcat ----------
// Interleave: bid in [0, ib): deg block iff (bid%9==8 && bid/9<db); else round block
// rid = bid - min(bid/9, db) (injective, covers [0, rb)). ib = max(rb+db, 9*db).
__global__ __launch_bounds__(256) void prep_kernel(
    const float* __restrict__ x, unsigned short* __restrict__ xb, int n4,
    const int* __restrict__ ei, int* __restrict__ deg, int E,
    const float* __restrict__ W1, const float* __restrict__ W2, const float* __restrict__ W3,
    const float* __restrict__ Wp1, const float* __restrict__ Wt1,
    unsigned short* __restrict__ W1hi, unsigned short* __restrict__ W1lo,
    unsigned short* __restrict__ W2hi, unsigned short* __restrict__ W2lo,
    unsigned short* __restrict__ W3hi, unsigned short* __restrict__ W3lo,
    unsigned short* __restrict__ Wchi, unsigned short* __restrict__ Wclo,
    const float* __restrict__ bp1, const float* __restrict__ bt1, float* __restrict__ bcat,
    int rb, int db, int ib, int Nn) {
    int bid = blockIdx.x;
    int tid = threadIdx.x;
    if (bid < ib) {
        int d9 = bid / 9, r9 = bid % 9;
        if (r9 == 8 && d9 < db) {  // degree: 4 edges/thread, fire-and-forget atomics
            int base = (d9 * 256 + tid) * 4;
#pragma unroll
            for (int k = 0; k < 4; ++k) {
                int e = base + k;
                if (e < E) atomicAdd(&deg[ei[E + e]], 1);
            }
        } else {  // round x -> xb (sliced)
            int rid = bid - min(d9, db);
            if (rid < rb) {
                int i = rid * 256 + tid;
                if (i < n4) {
                    float4 v = *reinterpret_cast<const float4*>(x + (size_t)i * 4);
                    int node = i >> 5, f = (i & 31) * 4;
                    ushort4 o;
                    o.x = f2b(v.x); o.y = f2b(v.y); o.z = f2b(v.z); o.w = f2b(v.w);
                    *reinterpret_cast<ushort4*>(xb + ((size_t)(f >> 4) * Nn + node) * 16 + (f & 15)) = o;
                }
            }
        }
        return;
    }
    int b = bid - ib;
    if (b < 288) {  // weight split+transpose
        const float* W;
        unsigned short *Whi, *Wlo;
        int lb, ncshift, total;
        if (b < 64)       { W = W1;  Whi = W1hi; Wlo = W1lo; lb = b;       ncshift = 7; total = 16384; }
        else if (b < 128) { W = W2;  Whi = W2hi; Wlo = W2lo; lb = b - 64;  ncshift = 7; total = 16384; }
        else if (b < 192) { W = W3;  Whi = W3hi; Wlo = W3lo; lb = b - 128; ncshift = 7; total = 16384; }
        else if (b < 256) { W = Wp1; Whi = Wchi; Wlo = Wclo; lb = b - 192; ncshift = 7; total = 16384; }
        else              { W = Wt1; Whi = Wchi + 128 * 128; Wlo = Wclo + 128 * 128; lb = b - 256; ncshift = 6; total = 8192; }
        int idx = lb * 256 + tid;
        if (idx < total) {
            int k = idx >> ncshift;
            int n = idx - (k << ncshift);
            float a = W[idx];
            unsigned short hb = f2b(a);
            Whi[(n << 7) + k] = hb;
            Wlo[(n << 7) + k] = f2b(a - b2f(hb));
        }
        return;
    }
    // bcat
    if (tid < 128) bcat[tid] = bp1[tid];
    else if (tid < 192) bcat[tid] = bt1[tid - 128];
}

// ---------- hierarchical exclusive scan (1024 elems / block) ----------
__global__ __launch_bounds__(256) void scan1_kernel(const int* __restrict__ deg,
                                                    int* __restrict__ excl,
                                                    int* __restrict__ chunk_sum, int n) {
    __shared__ int s[256];
    int tid = threadIdx.x;
    int base = blockIdx.x * 1024 + tid * 4;
    int v[4], sum = 0;
#pragma unroll
    for (int j = 0; j < 4; ++j) {
        v[j] = (base + j < n) ? deg[base + j] : 0;
        sum += v[j];
    }
    s[tid] = sum;
    __syncthreads();
    for (int off = 1; off < 256; off <<= 1) {
        int t = (tid >= off) ? s[tid - off] : 0;
        __syncthreads();
        s[tid] += t;
        __syncthreads();
    }
    int run = s[tid] - sum;
#pragma unroll
    for (int j = 0; j < 4; ++j) {
        if (base + j < n) excl[base + j] = run;
        run += v[j];
    }
    if (tid == 255) chunk_sum[blockIdx.x] = s[255];
}

__global__ __launch_bounds__(128) void scan2_kernel(const int* __restrict__ chunk_sum,
                                                    int* __restrict__ chunk_off, int nc) {
    __shared__ int s[128];
    int tid = threadIdx.x;
    int v = (tid < nc) ? chunk_sum[tid] : 0;
    s[tid] = v;
    __syncthreads();
    for (int off = 1; off < 128; off <<= 1) {
        int t = (tid >= off) ? s[tid - off] : 0;
        __syncthreads();
        s[tid] += t;
        __syncthreads();
    }
    if (tid < nc) chunk_off[tid] = s[tid] - v;
}

__global__ __launch_bounds__(256) void scan3_kernel(const int* __restrict__ excl,
                                                    const int* __restrict__ chunk_off,
                                                    const int* __restrict__ deg,
                                                    int* __restrict__ row_ptr,
                                                    int* __restrict__ fill_pos,
                                                    float* __restrict__ dinv, int n, int E) {
    int i = blockIdx.x * 256 + threadIdx.x;
    if (i < n) {
        int r = excl[i] + chunk_off[i >> 10];
        row_ptr[i] = r;
        fill_pos[i] = r;
        dinv[i] = rsqrtf((float)deg[i] + 1.0f);
    }
    if (i == 0) row_ptr[n] = E;
}

// ---------- shared GEMM accumulate body (sliced A) ----------
template <int NT>
static __device__ __forceinline__ void gemm_acc(const unsigned short* __restrict__ A,
                                                const unsigned short* __restrict__ Whi,
                                                const unsigned short* __restrict__ Wlo,
                                                int arow, int m16, int quad, f32x4* acc, int Nn) {
#pragma unroll
    for (int kb = 0; kb < 4; ++kb) {
        int f0 = kb * 32 + quad * 8;
        BU a;
        a.u = *reinterpret_cast<const u16x8*>(A + ((size_t)(f0 >> 4) * Nn + arow) * 16 + (f0 & 15));
#pragma unroll
        for (int t = 0; t < NT; ++t) {
            size_t woff = (size_t)(t * 16 + m16) * 128 + f0;
            BU bh, bl;
            bh.u = *reinterpret_cast<const u16x8*>(Whi + woff);
            bl.u = *reinterpret_cast<const u16x8*>(Wlo + woff);
            acc[t] = __builtin_amdgcn_mfma_f32_16x16x32_bf16(a.b, bh.b, acc[t], 0, 0, 0);
            acc[t] = __builtin_amdgcn_mfma_f32_16x16x32_bf16(a.b, bl.b, acc[t], 0, 0, 0);
        }
    }
}

// epilogue: C(sliced) = (A@W) * dinv[row] -> bf16
template <int NT>
static __device__ __forceinline__ void gemm_store_scaled(const float* __restrict__ dinv,
                                                         unsigned short* __restrict__ C,
                                                         int row_base, int m16, int quad,
                                                         f32x4* acc, int nrows, int Nn) {
#pragma unroll
    for (int t = 0; t < NT; ++t) {
#pragma unroll
        for (int r = 0; r < 4; ++r) {
            int row = row_base + quad * 4 + r;
            if (row < nrows)
                C[((size_t)t * Nn + row) * 16 + m16] = f2b(acc[t][r] * dinv[row]);
        }
    }
}

// plain GEMM kernel (layers 2,3)
template <int NT>
__global__ __launch_bounds__(256) void gemm_kernel(const unsigned short* __restrict__ A,
                                                   const unsigned short* __restrict__ Whi,
                                                   const unsigned short* __restrict__ Wlo,
                                                   const float* __restrict__ dinv,
                                                   unsigned short* __restrict__ C, int nrows) {
    const int tid = threadIdx.x;
    const int wave = tid >> 6, lane = tid & 63;
    const int m16 = lane & 15, quad = lane >> 4;
    const int row_base = blockIdx.x * 64 + wave * 16;
    int arow = row_base + m16;
    if (arow >= nrows) arow = nrows - 1;
    f32x4 acc[NT] = {};
    gemm_acc<NT>(A, Whi, Wlo, arow, m16, quad, acc, nrows);
    gemm_store_scaled<NT>(dinv, C, row_base, m16, quad, acc, nrows, nrows);
}

// ---------- fused: layer-1 GEMM || CSR fill (1:1 interleave, 4 edges/thread) ----------
__global__ __launch_bounds__(256) void fg_kernel(const unsigned short* __restrict__ A,
                                                 const unsigned short* __restrict__ Whi,
                                                 const unsigned short* __restrict__ Wlo,
                                                 const float* __restrict__ dinv,
                                                 unsigned short* __restrict__ C, int nrows,
                                                 int gb,
                                                 const int* __restrict__ ei,
                                                 int* __restrict__ fill_pos,
                                                 int* __restrict__ csr_src, int E) {
    const int bid = blockIdx.x;
    const int tid = threadIdx.x;
    bool isg = ((bid & 1) == 0) && ((bid >> 1) < gb);
    if (isg) {
        const int wave = tid >> 6, lane = tid & 63;
        const int m16 = lane & 15, quad = lane >> 4;
        const int row_base = (bid >> 1) * 64 + wave * 16;
        int arow = row_base + m16;
        if (arow >= nrows) arow = nrows - 1;
        f32x4 acc[8] = {};
        gemm_acc<8>(A, Whi, Wlo, arow, m16, quad, acc, nrows);
        gemm_store_scaled<8>(dinv, C, row_base, m16, quad, acc, nrows, nrows);
    } else {
        int fid = bid - min((bid + 1) >> 1, gb);
        int base = (fid * 256 + tid) * 4;
        int dsts[4], srcs[4], ps[4];
#pragma unroll
        for (int k = 0; k < 4; ++k) {
            int e = base + k;
            dsts[k] = (e < E) ? ei[E + e] : -1;
            srcs[k] = (e < E) ? ei[e] : 0;
        }
#pragma unroll
        for (int k = 0; k < 4; ++k)
            if (dsts[k] >= 0) ps[k] = atomicAdd(&fill_pos[dsts[k]], 1);
#pragma unroll
        for (int k = 0; k < 4; ++k)
            if (dsts[k] >= 0) {
                int p = (unsigned)ps[k] < (unsigned)E ? ps[k] : E - 1;  // defensive
                __builtin_nontemporal_store(srcs[k], &csr_src[p]);
            }
    }
}

// ---------- sliced pull: slice = bid&7 (XCD affinity), lane-pair per node ----------
// out(sliced) = relu(dinv[i]*(sum_in hs[src] + hs[i]) + b)
__global__ __launch_bounds__(256) void pull_kernel(const unsigned short* __restrict__ hs,
                                                   const int* __restrict__ row_ptr,
                                                   const int* __restrict__ csr_src,
                                                   const float* __restrict__ dinv,
                                                   const float* __restrict__ bias,
                                                   unsigned short* __restrict__ out, int n) {
    const int tid = threadIdx.x;
    const int wave = tid >> 6, lane = tid & 63;
    const int slice = blockIdx.x & 7;
    const int node = (blockIdx.x >> 3) * 128 + wave * 32 + (lane >> 1);
    const int half = lane & 1;
    if (node >= n) return;
    const unsigned short* hss = hs + (size_t)slice * n * 16 + half * 8;
    float a[8] = {0.f, 0.f, 0.f, 0.f, 0.f, 0.f, 0.f, 0.f};
    int s0 = row_ptr[node], s1 = row_ptr[node + 1];
    int e = s0;
    for (; e + 4 <= s1; e += 4) {
        int src0 = csr_src[e], src1 = csr_src[e + 1];
        int src2 = csr_src[e + 2], src3 = csr_src[e + 3];
        src0 = (unsigned)src0 < (unsigned)n ? src0 : 0;  // defensive
        src1 = (unsigned)src1 < (unsigned)n ? src1 : 0;
        src2 = (unsigned)src2 < (unsigned)n ? src2 : 0;
        src3 = (unsigned)src3 < (unsigned)n ? src3 : 0;
        BU h0, h1, h2, h3;
        h0.u = *reinterpret_cast<const u16x8*>(hss + (size_t)src0 * 16);
        h1.u = *reinterpret_cast<const u16x8*>(hss + (size_t)src1 * 16);
        h2.u = *reinterpret_cast<const u16x8*>(hss + (size_t)src2 * 16);
        h3.u = *reinterpret_cast<const u16x8*>(hss + (size_t)src3 * 16);
#pragma unroll
        for (int j = 0; j < 8; ++j)
            a[j] += (b2f(h0.u[j]) + b2f(h1.u[j])) + (b2f(h2.u[j]) + b2f(h3.u[j]));
    }
    for (; e < s1; ++e) {
        int src0 = csr_src[e];
        src0 = (unsigned)src0 < (unsigned)n ? src0 : 0;
        BU h0;
        h0.u = *reinterpret_cast<const u16x8*>(hss + (size_t)src0 * 16);
#pragma unroll
        for (int j = 0; j < 8; ++j) a[j] += b2f(h0.u[j]);
    }
    BU sv;
    sv.u = *reinterpret_cast<const u16x8*>(hss + (size_t)node * 16);
    float d = dinv[node];
    BU o;
#pragma unroll
    for (int j = 0; j < 8; ++j)
        o.u[j] = f2b(fmaxf((a[j] + b2f(sv.u[j])) * d + bias[slice * 16 + half * 8 + j], 0.f));
    *reinterpret_cast<u16x8*>(out + ((size_t)slice * n + node) * 16 + half * 8) = o.u;
}

// ---------- fused heads GEMM + in-register reduction -> out[N,3] f32 ----------
__global__ __launch_bounds__(256) void gemmh_kernel(const unsigned short* __restrict__ A,
                                                    const unsigned short* __restrict__ Whi,
                                                    const unsigned short* __restrict__ Wlo,
                                                    const float* __restrict__ bcat,
                                                    const float* __restrict__ Wp2,
                                                    const float* __restrict__ bp2,
                                                    const float* __restrict__ Wt2,
                                                    const float* __restrict__ bt2,
                                                    float* __restrict__ out, int nrows) {
    const int tid = threadIdx.x;
    const int wave = tid >> 6, lane = tid & 63;
    const int m16 = lane & 15, quad = lane >> 4;
    const int row_base = blockIdx.x * 64 + wave * 16;
    int arow = row_base + m16;
    if (arow >= nrows) arow = nrows - 1;
    f32x4 acc[12] = {};
    gemm_acc<12>(A, Whi, Wlo, arow, m16, quad, acc, nrows);
#pragma unroll
    for (int r = 0; r < 4; ++r) {
        int row = row_base + quad * 4 + r;
        float p0 = 0.f, p1 = 0.f, tt = 0.f;
#pragma unroll
        for (int t = 0; t < 12; ++t) {
            int c = t * 16 + m16;
            float v = fmaxf(acc[t][r] + bcat[c], 0.f);
            if (t < 8) {
                p0 += v * Wp2[c * 2 + 0];
                p1 += v * Wp2[c * 2 + 1];
            } else {
                tt += v * Wt2[c - 128];
            }
        }
#pragma unroll
        for (int mask = 1; mask < 16; mask <<= 1) {
            p0 += __shfl_xor(p0, mask);
            p1 += __shfl_xor(p1, mask);
            tt += __shfl_xor(tt, mask);
        }
        if (m16 == 0 && row < nrows) {
            out[(size_t)row * 3 + 0] = p0 + bp2[0];
            out[(size_t)row * 3 + 1] = p1 + bp2[1];
            out[(size_t)row * 3 + 2] = tt + bt2[0];
        }
    }
}

// ---------- launcher ----------
extern "C" void kernel_launch(void* const* d_in, const int* in_sizes, int n_in,
                              void* d_out, int out_size, void* d_ws, size_t ws_size,
                              hipStream_t stream) {
    const int N = in_sizes[0] / 128;
    const int E = in_sizes[1] / 2;

    const float* x   = (const float*)d_in[0];
    const int* ei    = (const int*)d_in[1];
    const float* W1  = (const float*)d_in[2];
    const float* b1  = (const float*)d_in[3];
    const float* W2  = (const float*)d_in[4];
    const float* b2  = (const float*)d_in[5];
    const float* W3  = (const float*)d_in[6];
    const float* b3  = (const float*)d_in[7];
    const float* Wp1 = (const float*)d_in[8];
    const float* bp1 = (const float*)d_in[9];
    const float* Wp2 = (const float*)d_in[10];
    const float* bp2 = (const float*)d_in[11];
    const float* Wt1 = (const float*)d_in[12];
    const float* bt1 = (const float*)d_in[13];
    const float* Wt2 = (const float*)d_in[14];
    const float* bt2 = (const float*)d_in[15];
    float* out = (float*)d_out;

    char* ws = (char*)d_ws;
    size_t off = 0;
    auto alloc = [&](size_t bytes) {
        void* p = ws + off;
        off += (bytes + 255) & ~(size_t)255;
        return p;
    };
    int* deg        = (int*)alloc((size_t)N * 4);
    float* dinv     = (float*)alloc((size_t)N * 4);
    int* excl       = (int*)alloc((size_t)N * 4);
    int* row_ptr    = (int*)alloc((size_t)(N + 1) * 4);
    int* fill_pos   = (int*)alloc((size_t)N * 4);
    int* chunk_sum  = (int*)alloc(128 * 4);
    int* chunk_off  = (int*)alloc(128 * 4);
    int* csr_src    = (int*)alloc((size_t)E * 4);
    unsigned short* W1hi = (unsigned short*)alloc(16384 * 2);
    unsigned short* W1lo = (unsigned short*)alloc(16384 * 2);
    unsigned short* W2hi = (unsigned short*)alloc(16384 * 2);
    unsigned short* W2lo = (unsigned short*)alloc(16384 * 2);
    unsigned short* W3hi = (unsigned short*)alloc(16384 * 2);
    unsigned short* W3lo = (unsigned short*)alloc(16384 * 2);
    unsigned short* Wchi = (unsigned short*)alloc(192 * 128 * 2);
    unsigned short* Wclo = (unsigned short*)alloc(192 * 128 * 2);
    float* bcat          = (float*)alloc(192 * 4);
    unsigned short* xb   = (unsigned short*)alloc((size_t)N * 128 * 2);
    unsigned short* hs   = (unsigned short*)alloc((size_t)N * 128 * 2);
    unsigned short* hb   = (unsigned short*)alloc((size_t)N * 128 * 2);

    hipMemsetAsync(deg, 0, (size_t)N * 4, stream);

    // fused prep (round || deg interleaved 8:1 with exact coverage, then weights, bcat)
    const int n4 = N * 32;
    const int rb = (n4 + 255) / 256;
    const int db = (E + 1023) / 1024;
    const int ib = (rb + db > 9 * db) ? (rb + db) : (9 * db);
    prep_kernel<<<ib + 288 + 1, 256, 0, stream>>>(
        x, xb, n4, ei, deg, E, W1, W2, W3, Wp1, Wt1,
        W1hi, W1lo, W2hi, W2lo, W3hi, W3lo, Wchi, Wclo, bp1, bt1, bcat, rb, db, ib, N);

    // CSR scan
    const int nb1 = (N + 1023) / 1024;
    scan1_kernel<<<nb1, 256, 0, stream>>>(deg, excl, chunk_sum, N);
    scan2_kernel<<<1, 128, 0, stream>>>(chunk_sum, chunk_off, nb1);
    scan3_kernel<<<(N + 255) / 256, 256, 0, stream>>>(excl, chunk_off, deg, row_ptr, fill_pos, dinv, N, E);

    const int gb = (N + 63) / 64;
    const int fb = ((E + 3) / 4 + 255) / 256;
    const int pull_blocks = 8 * ((N + 127) / 128);

    // layer 1 GEMM || CSR fill (1:1 interleave)
    fg_kernel<<<gb + fb, 256, 0, stream>>>(xb, W1hi, W1lo, dinv, hs, N, gb, ei, fill_pos, csr_src, E);
    pull_kernel<<<pull_blocks, 256, 0, stream>>>(hs, row_ptr, csr_src, dinv, b1, hb, N);
    // layer 2
    gemm_kernel<8><<<gb, 256, 0, stream>>>(hb, W2hi, W2lo, dinv, hs, N);
    pull_kernel<<<pull_blocks, 256, 0, stream>>>(hs, row_ptr, csr_src, dinv, b2, hb, N);
    // layer 3
    gemm_kernel<8><<<gb, 256, 0, stream>>>(hb, W3hi, W3lo, dinv, hs, N);
    pull_kernel<<<pull_blocks, 256, 0, stream>>>(hs, row_ptr, csr_src, dinv, b3, hb, N);

    // fused heads
    gemmh_kernel<<<gb, 256, 0, stream>>>(hb, Wchi, Wclo, bcat, Wp2, bp2, Wt2, bt2, out, N);
}

// Round 7
// 693.698 us; speedup vs baseline: 1.1146x; 1.1146x over previous
//
#include <hip/hip_runtime.h>

// ---------- types / helpers ----------
typedef __bf16 bf16x8 __attribute__((ext_vector_type(8)));
typedef unsigned short u16x8 __attribute__((ext_vector_type(8)));
typedef float f32x4 __attribute__((ext_vector_type(4)));

union BU {
    u16x8 u;
    bf16x8 b;
};

static __device__ __forceinline__ float b2f(unsigned short u) {
    return __uint_as_float(((unsigned)u) << 16);
}
static __device__ __forceinline__ unsigned short f2b(float f) {
    unsigned u = __float_as_uint(f);
    unsigned r = (u + 0x7FFF + ((u >> 16) & 1)) >> 16;  // RNE
    return (unsigned short)r;
}

// ---------- fused prep: round(x->xb dense) || deg atomics, then wsplit + bcat ----------
// Interleave: bid in [0, ib): deg block iff (bid%9==8 && bid/9<db); else round block
// rid = bid - min(bid/9, db). ib = max(rb+db, 9*db).
__global__ __launch_bounds__(256) void prep_kernel(
    const float* __restrict__ x, unsigned short* __restrict__ xb, int n4,
    const int* __restrict__ ei, int* __restrict__ deg, int E,
    const float* __restrict__ W1, const float* __restrict__ W2, const float* __restrict__ W3,
    const float* __restrict__ Wp1, const float* __restrict__ Wt1,
    unsigned short* __restrict__ W1hi, unsigned short* __restrict__ W1lo,
    unsigned short* __restrict__ W2hi, unsigned short* __restrict__ W2lo,
    unsigned short* __restrict__ W3hi, unsigned short* __restrict__ W3lo,
    unsigned short* __restrict__ Wchi, unsigned short* __restrict__ Wclo,
    const float* __restrict__ bp1, const float* __restrict__ bt1, float* __restrict__ bcat,
    int rb, int db, int ib) {
    int bid = blockIdx.x;
    int tid = threadIdx.x;
    if (bid < ib) {
        int d9 = bid / 9, r9 = bid % 9;
        if (r9 == 8 && d9 < db) {  // degree: 4 edges/thread, fire-and-forget atomics
            int base = (d9 * 256 + tid) * 4;
#pragma unroll
            for (int k = 0; k < 4; ++k) {
                int e = base + k;
                if (e < E) atomicAdd(&deg[ei[E + e]], 1);
            }
        } else {  // round x -> xb (dense)
            int rid = bid - min(d9, db);
            if (rid < rb) {
                int i = rid * 256 + tid;
                if (i < n4) {
                    float4 v = *reinterpret_cast<const float4*>(x + (size_t)i * 4);
                    ushort4 o;
                    o.x = f2b(v.x); o.y = f2b(v.y); o.z = f2b(v.z); o.w = f2b(v.w);
                    *reinterpret_cast<ushort4*>(xb + (size_t)i * 4) = o;
                }
            }
        }
        return;
    }
    int b = bid - ib;
    if (b < 288) {  // weight split+transpose
        const float* W;
        unsigned short *Whi, *Wlo;
        int lb, ncshift, total;
        if (b < 64)       { W = W1;  Whi = W1hi; Wlo = W1lo; lb = b;       ncshift = 7; total = 16384; }
        else if (b < 128) { W = W2;  Whi = W2hi; Wlo = W2lo; lb = b - 64;  ncshift = 7; total = 16384; }
        else if (b < 192) { W = W3;  Whi = W3hi; Wlo = W3lo; lb = b - 128; ncshift = 7; total = 16384; }
        else if (b < 256) { W = Wp1; Whi = Wchi; Wlo = Wclo; lb = b - 192; ncshift = 7; total = 16384; }
        else              { W = Wt1; Whi = Wchi + 128 * 128; Wlo = Wclo + 128 * 128; lb = b - 256; ncshift = 6; total = 8192; }
        int idx = lb * 256 + tid;
        if (idx < total) {
            int k = idx >> ncshift;
            int n = idx - (k << ncshift);
            float a = W[idx];
            unsigned short hb = f2b(a);
            Whi[(n << 7) + k] = hb;
            Wlo[(n << 7) + k] = f2b(a - b2f(hb));
        }
        return;
    }
    // bcat
    if (tid < 128) bcat[tid] = bp1[tid];
    else if (tid < 192) bcat[tid] = bt1[tid - 128];
}

// ---------- hierarchical exclusive scan (1024 elems / block) ----------
__global__ __launch_bounds__(256) void scan1_kernel(const int* __restrict__ deg,
                                                    int* __restrict__ excl,
                                                    int* __restrict__ chunk_sum, int n) {
    __shared__ int s[256];
    int tid = threadIdx.x;
    int base = blockIdx.x * 1024 + tid * 4;
    int v[4], sum = 0;
#pragma unroll
    for (int j = 0; j < 4; ++j) {
        v[j] = (base + j < n) ? deg[base + j] : 0;
        sum += v[j];
    }
    s[tid] = sum;
    __syncthreads();
    for (int off = 1; off < 256; off <<= 1) {
        int t = (tid >= off) ? s[tid - off] : 0;
        __syncthreads();
        s[tid] += t;
        __syncthreads();
    }
    int run = s[tid] - sum;
#pragma unroll
    for (int j = 0; j < 4; ++j) {
        if (base + j < n) excl[base + j] = run;
        run += v[j];
    }
    if (tid == 255) chunk_sum[blockIdx.x] = s[255];
}

__global__ __launch_bounds__(128) void scan2_kernel(const int* __restrict__ chunk_sum,
                                                    int* __restrict__ chunk_off, int nc) {
    __shared__ int s[128];
    int tid = threadIdx.x;
    int v = (tid < nc) ? chunk_sum[tid] : 0;
    s[tid] = v;
    __syncthreads();
    for (int off = 1; off < 128; off <<= 1) {
        int t = (tid >= off) ? s[tid - off] : 0;
        __syncthreads();
        s[tid] += t;
        __syncthreads();
    }
    if (tid < nc) chunk_off[tid] = s[tid] - v;
}

__global__ __launch_bounds__(256) void scan3_kernel(const int* __restrict__ excl,
                                                    const int* __restrict__ chunk_off,
                                                    const int* __restrict__ deg,
                                                    int* __restrict__ row_ptr,
                                                    int* __restrict__ fill_pos,
                                                    float* __restrict__ dinv, int n, int E) {
    int i = blockIdx.x * 256 + threadIdx.x;
    if (i < n) {
        int r = excl[i] + chunk_off[i >> 10];
        row_ptr[i] = r;
        fill_pos[i] = r;
        dinv[i] = rsqrtf((float)deg[i] + 1.0f);
    }
    if (i == 0) row_ptr[n] = E;
}

// ---------- shared GEMM accumulate body (dense A) ----------
template <int NT>
static __device__ __forceinline__ void gemm_acc(const unsigned short* __restrict__ A,
                                                const unsigned short* __restrict__ Whi,
                                                const unsigned short* __restrict__ Wlo,
                                                int arow, int m16, int quad, f32x4* acc) {
    const unsigned short* Arow = A + (size_t)arow * 128 + quad * 8;
#pragma unroll
    for (int kb = 0; kb < 4; ++kb) {
        BU a;
        a.u = *reinterpret_cast<const u16x8*>(Arow + kb * 32);
#pragma unroll
        for (int t = 0; t < NT; ++t) {
            size_t woff = (size_t)(t * 16 + m16) * 128 + quad * 8 + kb * 32;
            BU bh, bl;
            bh.u = *reinterpret_cast<const u16x8*>(Whi + woff);
            bl.u = *reinterpret_cast<const u16x8*>(Wlo + woff);
            acc[t] = __builtin_amdgcn_mfma_f32_16x16x32_bf16(a.b, bh.b, acc[t], 0, 0, 0);
            acc[t] = __builtin_amdgcn_mfma_f32_16x16x32_bf16(a.b, bl.b, acc[t], 0, 0, 0);
        }
    }
}

// epilogue: C = (A@W) * dinv[row] -> bf16 (dense)
template <int NT>
static __device__ __forceinline__ void gemm_store_scaled(const float* __restrict__ dinv,
                                                         unsigned short* __restrict__ C,
                                                         int row_base, int m16, int quad,
                                                         f32x4* acc, int nrows) {
#pragma unroll
    for (int t = 0; t < NT; ++t) {
#pragma unroll
        for (int r = 0; r < 4; ++r) {
            int row = row_base + quad * 4 + r;
            if (row < nrows)
                C[(size_t)row * (NT * 16) + t * 16 + m16] = f2b(acc[t][r] * dinv[row]);
        }
    }
}

// plain GEMM kernel (layers 2,3)
template <int NT>
__global__ __launch_bounds__(256) void gemm_kernel(const unsigned short* __restrict__ A,
                                                   const unsigned short* __restrict__ Whi,
                                                   const unsigned short* __restrict__ Wlo,
                                                   const float* __restrict__ dinv,
                                                   unsigned short* __restrict__ C, int nrows) {
    const int tid = threadIdx.x;
    const int wave = tid >> 6, lane = tid & 63;
    const int m16 = lane & 15, quad = lane >> 4;
    const int row_base = blockIdx.x * 64 + wave * 16;
    int arow = row_base + m16;
    if (arow >= nrows) arow = nrows - 1;
    f32x4 acc[NT] = {};
    gemm_acc<NT>(A, Whi, Wlo, arow, m16, quad, acc);
    gemm_store_scaled<NT>(dinv, C, row_base, m16, quad, acc, nrows);
}

// ---------- fused: layer-1 GEMM || CSR fill (interleave, 8 edges/thread) ----------
__global__ __launch_bounds__(256) void fg_kernel(const unsigned short* __restrict__ A,
                                                 const unsigned short* __restrict__ Whi,
                                                 const unsigned short* __restrict__ Wlo,
                                                 const float* __restrict__ dinv,
                                                 unsigned short* __restrict__ C, int nrows,
                                                 int gb, int fbn,
                                                 const int* __restrict__ ei,
                                                 int* __restrict__ fill_pos,
                                                 int* __restrict__ csr_src, int E) {
    const int bid = blockIdx.x;
    const int tid = threadIdx.x;
    bool isg;
    int gid = 0, fid = 0;
    if (bid < 2 * fbn) {
        isg = !(bid & 1);
        gid = bid >> 1;
        fid = bid >> 1;
    } else {
        isg = true;
        gid = bid - fbn;
    }
    if (isg) {
        const int wave = tid >> 6, lane = tid & 63;
        const int m16 = lane & 15, quad = lane >> 4;
        const int row_base = gid * 64 + wave * 16;
        int arow = row_base + m16;
        if (arow >= nrows) arow = nrows - 1;
        f32x4 acc[8] = {};
        gemm_acc<8>(A, Whi, Wlo, arow, m16, quad, acc);
        gemm_store_scaled<8>(dinv, C, row_base, m16, quad, acc, nrows);
    } else {
        int base = (fid * 256 + tid) * 8;
        int dsts[8], srcs[8], ps[8];
#pragma unroll
        for (int k = 0; k < 8; ++k) {
            int e = base + k;
            dsts[k] = (e < E) ? ei[E + e] : -1;
            srcs[k] = (e < E) ? ei[e] : 0;
        }
#pragma unroll
        for (int k = 0; k < 8; ++k)
            if (dsts[k] >= 0) ps[k] = atomicAdd(&fill_pos[dsts[k]], 1);
#pragma unroll
        for (int k = 0; k < 8; ++k)
            if (dsts[k] >= 0) {
                int p = (unsigned)ps[k] < (unsigned)E ? ps[k] : E - 1;  // defensive
                __builtin_nontemporal_store(srcs[k], &csr_src[p]);
            }
    }
}

// ---------- wave-per-node pull ----------
// lane = slot(0..3) * 16 + chunk(0..15). Round r: slot s gathers 16B chunk of edge r*4+s.
// Index prefetch: one coalesced load of up to 64 indices, broadcast via shfl.
// out = relu(dinv[i]*(sum_in hs[src] + hs[i]) + b) -> bf16 dense
__global__ __launch_bounds__(256) void pull_kernel(const unsigned short* __restrict__ hs,
                                                   const int* __restrict__ row_ptr,
                                                   const int* __restrict__ csr_src,
                                                   const float* __restrict__ dinv,
                                                   const float* __restrict__ bias,
                                                   unsigned short* __restrict__ out, int n) {
    const int tid = threadIdx.x;
    const int wave = tid >> 6, lane = tid & 63;
    const int slot = lane >> 4, chunk = lane & 15;
    const int node = blockIdx.x * 4 + wave;
    if (node >= n) return;
    const int s0 = row_ptr[node], s1 = row_ptr[node + 1];

    // issue self-loop row load early (consumed in epilogue)
    BU sv;
    sv.u = *reinterpret_cast<const u16x8*>(hs + (size_t)node * 128 + chunk * 8);
    float d = dinv[node];

    float acc[8] = {};
    for (int base = s0; base < s1; base += 64) {
        const int m = min(64, s1 - base);
        int myidx = (lane < m) ? csr_src[base + lane] : 0;
        const int rounds = (m + 3) >> 2;
        int r = 0;
        for (; r + 2 <= rounds; r += 2) {
            int e0 = r * 4 + slot, e1 = e0 + 4;
            int src0 = __shfl(myidx, e0);
            int src1 = __shfl(myidx, e1);
            src0 = (unsigned)src0 < (unsigned)n ? src0 : 0;  // defensive
            src1 = (unsigned)src1 < (unsigned)n ? src1 : 0;
            bool ok0 = e0 < m, ok1 = e1 < m;
            BU h0, h1;
            if (ok0) h0.u = *reinterpret_cast<const u16x8*>(hs + (size_t)src0 * 128 + chunk * 8);
            if (ok1) h1.u = *reinterpret_cast<const u16x8*>(hs + (size_t)src1 * 128 + chunk * 8);
            if (ok0) {
#pragma unroll
                for (int j = 0; j < 8; ++j) acc[j] += b2f(h0.u[j]);
            }
            if (ok1) {
#pragma unroll
                for (int j = 0; j < 8; ++j) acc[j] += b2f(h1.u[j]);
            }
        }
        if (r < rounds) {
            int e0 = r * 4 + slot;
            int src0 = __shfl(myidx, e0);
            src0 = (unsigned)src0 < (unsigned)n ? src0 : 0;
            if (e0 < m) {
                BU h0;
                h0.u = *reinterpret_cast<const u16x8*>(hs + (size_t)src0 * 128 + chunk * 8);
#pragma unroll
                for (int j = 0; j < 8; ++j) acc[j] += b2f(h0.u[j]);
            }
        }
    }
    // reduce across the 4 slots (lane bits 4,5)
#pragma unroll
    for (int j = 0; j < 8; ++j) {
        acc[j] += __shfl_xor(acc[j], 16);
        acc[j] += __shfl_xor(acc[j], 32);
    }
    if (slot == 0) {
        BU o;
#pragma unroll
        for (int j = 0; j < 8; ++j)
            o.u[j] = f2b(fmaxf((acc[j] + b2f(sv.u[j])) * d + bias[chunk * 8 + j], 0.f));
        *reinterpret_cast<u16x8*>(out + (size_t)node * 128 + chunk * 8) = o.u;
    }
}

// ---------- fused heads GEMM + in-register reduction -> out[N,3] f32 ----------
__global__ __launch_bounds__(256) void gemmh_kernel(const unsigned short* __restrict__ A,
                                                    const unsigned short* __restrict__ Whi,
                                                    const unsigned short* __restrict__ Wlo,
                                                    const float* __restrict__ bcat,
                                                    const float* __restrict__ Wp2,
                                                    const float* __restrict__ bp2,
                                                    const float* __restrict__ Wt2,
                                                    const float* __restrict__ bt2,
                                                    float* __restrict__ out, int nrows) {
    const int tid = threadIdx.x;
    const int wave = tid >> 6, lane = tid & 63;
    const int m16 = lane & 15, quad = lane >> 4;
    const int row_base = blockIdx.x * 64 + wave * 16;
    int arow = row_base + m16;
    if (arow >= nrows) arow = nrows - 1;
    f32x4 acc[12] = {};
    gemm_acc<12>(A, Whi, Wlo, arow, m16, quad, acc);
#pragma unroll
    for (int r = 0; r < 4; ++r) {
        int row = row_base + quad * 4 + r;
        float p0 = 0.f, p1 = 0.f, tt = 0.f;
#pragma unroll
        for (int t = 0; t < 12; ++t) {
            int c = t * 16 + m16;
            float v = fmaxf(acc[t][r] + bcat[c], 0.f);
            if (t < 8) {
                p0 += v * Wp2[c * 2 + 0];
                p1 += v * Wp2[c * 2 + 1];
            } else {
                tt += v * Wt2[c - 128];
            }
        }
#pragma unroll
        for (int mask = 1; mask < 16; mask <<= 1) {
            p0 += __shfl_xor(p0, mask);
            p1 += __shfl_xor(p1, mask);
            tt += __shfl_xor(tt, mask);
        }
        if (m16 == 0 && row < nrows) {
            out[(size_t)row * 3 + 0] = p0 + bp2[0];
            out[(size_t)row * 3 + 1] = p1 + bp2[1];
            out[(size_t)row * 3 + 2] = tt + bt2[0];
        }
    }
}

// ---------- launcher ----------
extern "C" void kernel_launch(void* const* d_in, const int* in_sizes, int n_in,
                              void* d_out, int out_size, void* d_ws, size_t ws_size,
                              hipStream_t stream) {
    const int N = in_sizes[0] / 128;
    const int E = in_sizes[1] / 2;

    const float* x   = (const float*)d_in[0];
    const int* ei    = (const int*)d_in[1];
    const float* W1  = (const float*)d_in[2];
    const float* b1  = (const float*)d_in[3];
    const float* W2  = (const float*)d_in[4];
    const float* b2  = (const float*)d_in[5];
    const float* W3  = (const float*)d_in[6];
    const float* b3  = (const float*)d_in[7];
    const float* Wp1 = (const float*)d_in[8];
    const float* bp1 = (const float*)d_in[9];
    const float* Wp2 = (const float*)d_in[10];
    const float* bp2 = (const float*)d_in[11];
    const float* Wt1 = (const float*)d_in[12];
    const float* bt1 = (const float*)d_in[13];
    const float* Wt2 = (const float*)d_in[14];
    const float* bt2 = (const float*)d_in[15];
    float* out = (float*)d_out;

    char* ws = (char*)d_ws;
    size_t off = 0;
    auto alloc = [&](size_t bytes) {
        void* p = ws + off;
        off += (bytes + 255) & ~(size_t)255;
        return p;
    };
    int* deg        = (int*)alloc((size_t)N * 4);
    float* dinv     = (float*)alloc((size_t)N * 4);
    int* excl       = (int*)alloc((size_t)N * 4);
    int* row_ptr    = (int*)alloc((size_t)(N + 1) * 4);
    int* fill_pos   = (int*)alloc((size_t)N * 4);
    int* chunk_sum  = (int*)alloc(128 * 4);
    int* chunk_off  = (int*)alloc(128 * 4);
    int* csr_src    = (int*)alloc((size_t)E * 4);
    unsigned short* W1hi = (unsigned short*)alloc(16384 * 2);
    unsigned short* W1lo = (unsigned short*)alloc(16384 * 2);
    unsigned short* W2hi = (unsigned short*)alloc(16384 * 2);
    unsigned short* W2lo = (unsigned short*)alloc(16384 * 2);
    unsigned short* W3hi = (unsigned short*)alloc(16384 * 2);
    unsigned short* W3lo = (unsigned short*)alloc(16384 * 2);
    unsigned short* Wchi = (unsigned short*)alloc(192 * 128 * 2);
    unsigned short* Wclo = (unsigned short*)alloc(192 * 128 * 2);
    float* bcat          = (float*)alloc(192 * 4);
    unsigned short* xb   = (unsigned short*)alloc((size_t)N * 128 * 2);
    unsigned short* hs   = (unsigned short*)alloc((size_t)N * 128 * 2);
    unsigned short* hb   = (unsigned short*)alloc((size_t)N * 128 * 2);

    hipMemsetAsync(deg, 0, (size_t)N * 4, stream);

    // fused prep (round || deg interleaved, then weights, bcat)
    const int n4 = N * 32;
    const int rb = (n4 + 255) / 256;
    const int db = (E + 1023) / 1024;
    const int ib = (rb + db > 9 * db) ? (rb + db) : (9 * db);
    prep_kernel<<<ib + 288 + 1, 256, 0, stream>>>(
        x, xb, n4, ei, deg, E, W1, W2, W3, Wp1, Wt1,
        W1hi, W1lo, W2hi, W2lo, W3hi, W3lo, Wchi, Wclo, bp1, bt1, bcat, rb, db, ib);

    // CSR scan
    const int nb1 = (N + 1023) / 1024;
    scan1_kernel<<<nb1, 256, 0, stream>>>(deg, excl, chunk_sum, N);
    scan2_kernel<<<1, 128, 0, stream>>>(chunk_sum, chunk_off, nb1);
    scan3_kernel<<<(N + 255) / 256, 256, 0, stream>>>(excl, chunk_off, deg, row_ptr, fill_pos, dinv, N, E);

    const int gb = (N + 63) / 64;
    const int fbn = ((E + 7) / 8 + 255) / 256;
    const int pull_blocks = (N + 3) / 4;

    // layer 1 GEMM || CSR fill (1:1 interleave for first 2*fbn blocks)
    fg_kernel<<<gb + fbn, 256, 0, stream>>>(xb, W1hi, W1lo, dinv, hs, N, gb, fbn, ei, fill_pos, csr_src, E);
    pull_kernel<<<pull_blocks, 256, 0, stream>>>(hs, row_ptr, csr_src, dinv, b1, hb, N);
    // layer 2
    gemm_kernel<8><<<gb, 256, 0, stream>>>(hb, W2hi, W2lo, dinv, hs, N);
    pull_kernel<<<pull_blocks, 256, 0, stream>>>(hs, row_ptr, csr_src, dinv, b2, hb, N);
    // layer 3
    gemm_kernel<8><<<gb, 256, 0, stream>>>(hb, W3hi, W3lo, dinv, hs, N);
    pull_kernel<<<pull_blocks, 256, 0, stream>>>(hs, row_ptr, csr_src, dinv, b3, hb, N);

    // fused heads
    gemmh_kernel<<<gb, 256, 0, stream>>>(hb, Wchi, Wclo, bcat, Wp2, bp2, Wt2, bt2, out, N);
}